// Round 1
// 3664.824 us; speedup vs baseline: 1.0225x; 1.0225x over previous
//
#include <hip/hip_runtime.h>

#define N 512
#define C 256
#define TJ 16

// ---------------------------------------------------------------------------
// Fused edge kernel: one pass over edges computing all three per-edge linears.
//   e[j][c]  = n[i][c] * n[j][c] * s[i][j][c]        (staged once in LDS)
//   qhat[d]  = Wq[d,:].e + bq[d]   (khat, vhat analog)
//   scores[i][j] = sum_d qhat*khat*v[i][j][d]^2 / 16
//   veW[i][j][d] = (vhat[d]) * v[i][j][d]            (written iff WRITE_VE)
// Block: 256 threads (thread = output channel d), one (i, 16-j tile).
// W loads are software-pipelined (next-c4 prefetch) to hide L2 latency.
// ---------------------------------------------------------------------------
template<bool WRITE_VE>
__global__ __launch_bounds__(256) void k_edge(
    const float* __restrict__ n_g, const float* __restrict__ s_g,
    const float* __restrict__ v_g,
    const float* __restrict__ Wq, const float* __restrict__ bq,
    const float* __restrict__ Wk, const float* __restrict__ bk,
    const float* __restrict__ Wv, const float* __restrict__ bv,
    float* __restrict__ scores, float* __restrict__ veW)
{
    __shared__ float e_lds[TJ][C];
    __shared__ float part[4][TJ];
    const int i  = blockIdx.x;
    const int jb = blockIdx.y * TJ;
    const int t  = threadIdx.x;        // = channel d
    const int lane = t & 63, wid = t >> 6;

    const float ni = n_g[i * C + t];
    #pragma unroll
    for (int j = 0; j < TJ; ++j) {
        const int jj = jb + j;
        e_lds[j][t] = ni * n_g[jj * C + t] * s_g[((size_t)i * N + jj) * C + t];
    }
    __syncthreads();

    float aq[TJ], ak[TJ], av[TJ];
    const float bqd = bq[t], bkd = bk[t];
    const float bvd = WRITE_VE ? bv[t] : 0.0f;
    #pragma unroll
    for (int j = 0; j < TJ; ++j) { aq[j] = bqd; ak[j] = bkd; av[j] = bvd; }

    const float4* wq4 = (const float4*)(Wq + (size_t)t * C);
    const float4* wk4 = (const float4*)(Wk + (size_t)t * C);
    const float4* wv4 = (const float4*)(Wv + (size_t)t * C);

    // software-pipelined W loads: issue c4+1's loads before c4's FMA chain
    float4 qn = wq4[0], kn = wk4[0], vn;
    if constexpr (WRITE_VE) vn = wv4[0];

    for (int c4 = 0; c4 < C / 4; ++c4) {
        const float4 wq = qn, wk = kn;
        float4 wv;
        if constexpr (WRITE_VE) wv = vn;
        if (c4 + 1 < C / 4) {
            qn = wq4[c4 + 1];
            kn = wk4[c4 + 1];
            if constexpr (WRITE_VE) vn = wv4[c4 + 1];
        }
        #pragma unroll
        for (int j = 0; j < TJ; ++j) {
            const float4 ev = *(const float4*)&e_lds[j][c4 * 4];
            aq[j] += wq.x*ev.x + wq.y*ev.y + wq.z*ev.z + wq.w*ev.w;
            ak[j] += wk.x*ev.x + wk.y*ev.y + wk.z*ev.z + wk.w*ev.w;
            if constexpr (WRITE_VE)
                av[j] += wv.x*ev.x + wv.y*ev.y + wv.z*ev.z + wv.w*ev.w;
        }
    }

    #pragma unroll
    for (int j = 0; j < TJ; ++j) {
        const int jj = jb + j;
        const size_t eoff = ((size_t)i * N + jj) * C;
        const float vd = v_g[eoff + t];
        if constexpr (WRITE_VE) veW[eoff + t] = av[j] * vd;
        float r = aq[j] * ak[j] * vd * vd;
        #pragma unroll
        for (int off = 32; off > 0; off >>= 1)
            r += __shfl_down(r, off, 64);
        if (lane == 0) part[wid][j] = r;
    }
    __syncthreads();
    if (t < TJ) {
        const float ssum = part[0][t] + part[1][t] + part[2][t] + part[3][t];
        scores[(size_t)i * N + jb + t] = ssum * (1.0f / 16.0f);  // 1/sqrt(256)
    }
}

// ---------------------------------------------------------------------------
// Row softmax, in place (512 cols, 256 threads -> 2 each). Unchanged.
// ---------------------------------------------------------------------------
__global__ __launch_bounds__(256) void k_softmax(float* __restrict__ buf)
{
    __shared__ float red[4];
    const int i = blockIdx.x;
    const int t = threadIdx.x;
    const int lane = t & 63, wid = t >> 6;

    const float a = buf[(size_t)i * N + t];
    const float b = buf[(size_t)i * N + t + 256];
    float m = fmaxf(a, b);
    #pragma unroll
    for (int off = 32; off > 0; off >>= 1)
        m = fmaxf(m, __shfl_xor(m, off, 64));
    if (lane == 0) red[wid] = m;
    __syncthreads();
    m = fmaxf(fmaxf(red[0], red[1]), fmaxf(red[2], red[3]));

    const float ea = __expf(a - m), eb = __expf(b - m);
    float ssum = ea + eb;
    #pragma unroll
    for (int off = 32; off > 0; off >>= 1)
        ssum += __shfl_xor(ssum, off, 64);
    __syncthreads();               // red reuse
    if (lane == 0) red[wid] = ssum;
    __syncthreads();
    const float inv = 1.0f / (red[0] + red[1] + red[2] + red[3]);
    buf[(size_t)i * N + t]       = ea * inv;
    buf[(size_t)i * N + t + 256] = eb * inv;
}

// ---------------------------------------------------------------------------
// Gather (big-ws path): x[i][d] = sum_j attn[i][j] * veW[i][j][d],
// residual + L2-normalize. Memory-bound stream of 268 MB.
// ---------------------------------------------------------------------------
__global__ __launch_bounds__(256) void k_gather(
    const float* __restrict__ n_g, const float* __restrict__ veW,
    const float* __restrict__ attn, float* __restrict__ out)
{
    __shared__ float att_s[N];
    __shared__ float part[4];
    const int i = blockIdx.x;
    const int t = threadIdx.x;
    const int lane = t & 63, wid = t >> 6;

    att_s[t]       = attn[(size_t)i * N + t];
    att_s[t + 256] = attn[(size_t)i * N + t + 256];
    __syncthreads();

    const float* base = veW + (size_t)i * N * C + t;
    float xacc = 0.0f;
    for (int j = 0; j < N; j += 8) {
        const float p0 = base[(size_t)(j + 0) * C];
        const float p1 = base[(size_t)(j + 1) * C];
        const float p2 = base[(size_t)(j + 2) * C];
        const float p3 = base[(size_t)(j + 3) * C];
        const float p4 = base[(size_t)(j + 4) * C];
        const float p5 = base[(size_t)(j + 5) * C];
        const float p6 = base[(size_t)(j + 6) * C];
        const float p7 = base[(size_t)(j + 7) * C];
        xacc += att_s[j+0]*p0 + att_s[j+1]*p1 + att_s[j+2]*p2 + att_s[j+3]*p3
              + att_s[j+4]*p4 + att_s[j+5]*p5 + att_s[j+6]*p6 + att_s[j+7]*p7;
    }

    const float x = xacc + n_g[i * C + t];
    float sq = x * x;
    #pragma unroll
    for (int off = 32; off > 0; off >>= 1)
        sq += __shfl_xor(sq, off, 64);
    if (lane == 0) part[wid] = sq;
    __syncthreads();
    const float nrm = sqrtf(part[0] + part[1] + part[2] + part[3]);
    out[i * C + t] = x / nrm;
}

// ---------------------------------------------------------------------------
// Fallback output kernel (small-ws path): recompute e, one matvec, weighted
// sum over j. Same as previous session's k_out + pipelined Wv loads.
// ---------------------------------------------------------------------------
__global__ __launch_bounds__(256) void k_out(
    const float* __restrict__ n_g, const float* __restrict__ s_g,
    const float* __restrict__ v_g,
    const float* __restrict__ Wv, const float* __restrict__ bv,
    const float* __restrict__ attn, float* __restrict__ out)
{
    __shared__ float e_lds[TJ][C];
    __shared__ float part[4];
    const int i = blockIdx.x;
    const int t = threadIdx.x;
    const int lane = t & 63, wid = t >> 6;

    const float ni  = n_g[i * C + t];
    const float bvd = bv[t];
    const float4* wv4 = (const float4*)(Wv + (size_t)t * C);
    float xacc = 0.0f;

    for (int jt = 0; jt < N / TJ; ++jt) {
        const int jb = jt * TJ;
        __syncthreads();           // done with previous tile's e_lds
        #pragma unroll
        for (int j = 0; j < TJ; ++j) {
            const int jj = jb + j;
            e_lds[j][t] = ni * n_g[jj * C + t] * s_g[((size_t)i * N + jj) * C + t];
        }
        __syncthreads();

        float accv[TJ];
        #pragma unroll
        for (int j = 0; j < TJ; ++j) accv[j] = bvd;

        float4 vn = wv4[0];
        for (int c4 = 0; c4 < C / 4; ++c4) {
            const float4 wv = vn;
            if (c4 + 1 < C / 4) vn = wv4[c4 + 1];
            #pragma unroll
            for (int j = 0; j < TJ; ++j) {
                const float4 ev = *(const float4*)&e_lds[j][c4 * 4];
                accv[j] += wv.x*ev.x + wv.y*ev.y + wv.z*ev.z + wv.w*ev.w;
            }
        }
        #pragma unroll
        for (int j = 0; j < TJ; ++j) {
            const int jj = jb + j;
            const float a  = attn[(size_t)i * N + jj];
            const float vd = v_g[((size_t)i * N + jj) * C + t];
            xacc += a * accv[j] * vd;
        }
    }

    const float x = xacc + ni;
    float sq = x * x;
    #pragma unroll
    for (int off = 32; off > 0; off >>= 1)
        sq += __shfl_xor(sq, off, 64);
    if (lane == 0) part[wid] = sq;
    __syncthreads();
    const float nrm = sqrtf(part[0] + part[1] + part[2] + part[3]);
    out[i * C + t] = x / nrm;
}

extern "C" void kernel_launch(void* const* d_in, const int* in_sizes, int n_in,
                              void* d_out, int out_size, void* d_ws, size_t ws_size,
                              hipStream_t stream)
{
    const float* n_g = (const float*)d_in[0];
    const float* s_g = (const float*)d_in[1];
    const float* v_g = (const float*)d_in[2];
    const float* Wq  = (const float*)d_in[3];
    const float* bq  = (const float*)d_in[4];
    const float* Wk  = (const float*)d_in[5];
    const float* bk  = (const float*)d_in[6];
    const float* Wv  = (const float*)d_in[7];
    const float* bv  = (const float*)d_in[8];
    float* out = (float*)d_out;

    float* scores = (float*)d_ws;                       // N*N fp32 (1 MB)
    const size_t score_bytes = (size_t)N * N * sizeof(float);
    const size_t ve_bytes    = (size_t)N * N * C * sizeof(float);  // 268 MB
    float* veW = (float*)((char*)d_ws + score_bytes);
    const bool big_ws = ws_size >= score_bytes + ve_bytes;

    if (big_ws) {
        k_edge<true><<<dim3(N, N / TJ), 256, 0, stream>>>(
            n_g, s_g, v_g, Wq, bq, Wk, bk, Wv, bv, scores, veW);
        k_softmax<<<N, 256, 0, stream>>>(scores);
        k_gather <<<N, 256, 0, stream>>>(n_g, veW, scores, out);
    } else {
        k_edge<false><<<dim3(N, N / TJ), 256, 0, stream>>>(
            n_g, s_g, v_g, Wq, bq, Wk, bk, Wv, bv, scores, nullptr);
        k_softmax<<<N, 256, 0, stream>>>(scores);
        k_out    <<<N, 256, 0, stream>>>(n_g, s_g, v_g, Wv, bv, scores, out);
    }
}

// Round 2
// 1830.935 us; speedup vs baseline: 2.0467x; 2.0016x over previous
//
#include <hip/hip_runtime.h>

#define N 512
#define C 256

// New fused edge kernel tiling:
#define TJB 32   // j columns per block
#define JT  8    // j columns per thread
#define DT  4    // output channels per thread (contiguous)
// 256 threads = 64 d-groups (dg = t&63, d = 4*dg..4*dg+3) x 4 j-groups (jg = t>>6)

// Old fallback tiling:
#define TJ 16

__device__ __forceinline__ float f4c(const float4 v, const int i)
{
    return i == 0 ? v.x : i == 1 ? v.y : i == 2 ? v.z : v.w;
}

// ---------------------------------------------------------------------------
// Tiny tiled transpose: Wt[c][d] = W[d][c] for the three 256x256 weights.
// Grid (8, 8, 3), 256 threads (32x8 logical).
// ---------------------------------------------------------------------------
__global__ __launch_bounds__(256) void k_transpose(
    const float* __restrict__ Wq, const float* __restrict__ Wk,
    const float* __restrict__ Wv, float* __restrict__ wt_base)
{
    __shared__ float tile[32][33];
    const float* W = blockIdx.z == 0 ? Wq : blockIdx.z == 1 ? Wk : Wv;
    float* Wt = wt_base + (size_t)blockIdx.z * C * C;
    const int tx  = threadIdx.x & 31;
    const int ty0 = threadIdx.x >> 5;      // 0..7
    const int bx = blockIdx.x * 32;        // c block
    const int by = blockIdx.y * 32;        // d block
    #pragma unroll
    for (int r = 0; r < 4; ++r)
        tile[ty0 + r * 8][tx] = W[(size_t)(by + ty0 + r * 8) * C + bx + tx];
    __syncthreads();
    #pragma unroll
    for (int r = 0; r < 4; ++r)
        Wt[(size_t)(bx + ty0 + r * 8) * C + by + tx] = tile[tx][ty0 + r * 8];
}

// ---------------------------------------------------------------------------
// Fused edge kernel v2: register-tiled edge GEMM.
//   e[j][c] = n[i][c]*n[j][c]*s[i][j][c]   staged once in LDS (32 KB tile)
//   qhat/khat/vhat = W.e + b  via DT x JT register tile per thread
//   scores[i][j] = sum_d qhat*khat*v^2 / 16 ; veW = vhat*v (iff WRITE_VE)
// W is consumed TRANSPOSED (Wt[c][d]) so float4 loads along d are coalesced.
// LDS traffic per FMA is 4x lower than v1 (DT=4 amortization) -> LDS pipe
// no longer the bottleneck.
// ---------------------------------------------------------------------------
template<bool WRITE_VE>
__global__ __launch_bounds__(256, 2) void k_edge(
    const float* __restrict__ n_g, const float* __restrict__ s_g,
    const float* __restrict__ v_g,
    const float* __restrict__ wqt, const float* __restrict__ bq,
    const float* __restrict__ wkt, const float* __restrict__ bk,
    const float* __restrict__ wvt, const float* __restrict__ bv,
    float* __restrict__ scores, float* __restrict__ veW)
{
    __shared__ float e_lds[TJB][C];        // 32 KB
    const int i  = blockIdx.x;
    const int jb = blockIdx.y * TJB;
    const int t  = threadIdx.x;
    const int dg = t & 63;                 // lane = d-group
    const int jg = t >> 6;                 // wave = j-group
    const int jl = jg * JT;                // local j base for this thread

    // ---- stage e tile (coalesced, 2-way-free bank pattern) ----
    const float ni = n_g[i * C + t];
    #pragma unroll 4
    for (int j = 0; j < TJB; ++j) {
        const int jj = jb + j;
        e_lds[j][t] = ni * n_g[jj * C + t] * s_g[((size_t)i * N + jj) * C + t];
    }
    __syncthreads();

    // ---- register-tiled triple matvec ----
    float aq[DT][JT], ak[DT][JT], av[DT][JT];
    #pragma unroll
    for (int dr = 0; dr < DT; ++dr)
        #pragma unroll
        for (int jr = 0; jr < JT; ++jr) { aq[dr][jr] = 0.f; ak[dr][jr] = 0.f; av[dr][jr] = 0.f; }

    const float4* wq4 = (const float4*)wqt;   // float4 index: c*64 + dg
    const float4* wk4 = (const float4*)wkt;
    const float4* wv4 = (const float4*)wvt;

    for (int c4 = 0; c4 < C / 4; ++c4) {
        float4 ev[JT];                        // broadcast reads (uniform per wave)
        #pragma unroll
        for (int jr = 0; jr < JT; ++jr)
            ev[jr] = *(const float4*)&e_lds[jl + jr][c4 * 4];

        #pragma unroll
        for (int cs = 0; cs < 4; ++cs) {
            const int c = c4 * 4 + cs;
            const float4 wq = wq4[c * 64 + dg];
            const float4 wk = wk4[c * 64 + dg];
            const float4 wv = wv4[c * 64 + dg];
            #pragma unroll
            for (int jr = 0; jr < JT; ++jr) {
                const float e = f4c(ev[jr], cs);
                #pragma unroll
                for (int dr = 0; dr < DT; ++dr) {
                    aq[dr][jr] = fmaf(f4c(wq, dr), e, aq[dr][jr]);
                    ak[dr][jr] = fmaf(f4c(wk, dr), e, ak[dr][jr]);
                    av[dr][jr] = fmaf(f4c(wv, dr), e, av[dr][jr]);
                }
            }
        }
    }

    // ---- epilogue: bias, score reduce (one wave owns each j), veW write ----
    const float4 bq4 = *(const float4*)&bq[4 * dg];
    const float4 bk4 = *(const float4*)&bk[4 * dg];
    const float4 bv4 = *(const float4*)&bv[4 * dg];

    #pragma unroll
    for (int jr = 0; jr < JT; ++jr) {
        const int jj = jb + jl + jr;
        const size_t eoff = ((size_t)i * N + jj) * C + 4 * dg;
        const float4 vv = *(const float4*)&v_g[eoff];
        float r = 0.f;
        float4 veo;
        #pragma unroll
        for (int dr = 0; dr < DT; ++dr) {
            const float qh = aq[dr][jr] + f4c(bq4, dr);
            const float kh = ak[dr][jr] + f4c(bk4, dr);
            const float vd = f4c(vv, dr);
            r += qh * kh * vd * vd;
            const float vo = (av[dr][jr] + f4c(bv4, dr)) * vd;
            if (dr == 0) veo.x = vo; else if (dr == 1) veo.y = vo;
            else if (dr == 2) veo.z = vo; else veo.w = vo;
        }
        if constexpr (WRITE_VE)
            *(float4*)&veW[eoff] = veo;
        #pragma unroll
        for (int off = 32; off > 0; off >>= 1)
            r += __shfl_down(r, off, 64);
        if (dg == 0)
            scores[(size_t)i * N + jj] = r * (1.0f / 16.0f);   // 1/sqrt(256)
    }
}

// ---------------------------------------------------------------------------
// Row softmax, in place (512 cols, 256 threads -> 2 each). Unchanged.
// ---------------------------------------------------------------------------
__global__ __launch_bounds__(256) void k_softmax(float* __restrict__ buf)
{
    __shared__ float red[4];
    const int i = blockIdx.x;
    const int t = threadIdx.x;
    const int lane = t & 63, wid = t >> 6;

    const float a = buf[(size_t)i * N + t];
    const float b = buf[(size_t)i * N + t + 256];
    float m = fmaxf(a, b);
    #pragma unroll
    for (int off = 32; off > 0; off >>= 1)
        m = fmaxf(m, __shfl_xor(m, off, 64));
    if (lane == 0) red[wid] = m;
    __syncthreads();
    m = fmaxf(fmaxf(red[0], red[1]), fmaxf(red[2], red[3]));

    const float ea = __expf(a - m), eb = __expf(b - m);
    float ssum = ea + eb;
    #pragma unroll
    for (int off = 32; off > 0; off >>= 1)
        ssum += __shfl_xor(ssum, off, 64);
    __syncthreads();               // red reuse
    if (lane == 0) red[wid] = ssum;
    __syncthreads();
    const float inv = 1.0f / (red[0] + red[1] + red[2] + red[3]);
    buf[(size_t)i * N + t]       = ea * inv;
    buf[(size_t)i * N + t + 256] = eb * inv;
}

// ---------------------------------------------------------------------------
// Gather: x[i][d] = sum_j attn[i][j] * veW[i][j][d], residual + L2-normalize.
// Memory-bound stream of 268 MB. Unchanged.
// ---------------------------------------------------------------------------
__global__ __launch_bounds__(256) void k_gather(
    const float* __restrict__ n_g, const float* __restrict__ veW,
    const float* __restrict__ attn, float* __restrict__ out)
{
    __shared__ float att_s[N];
    __shared__ float part[4];
    const int i = blockIdx.x;
    const int t = threadIdx.x;
    const int lane = t & 63, wid = t >> 6;

    att_s[t]       = attn[(size_t)i * N + t];
    att_s[t + 256] = attn[(size_t)i * N + t + 256];
    __syncthreads();

    const float* base = veW + (size_t)i * N * C + t;
    float xacc = 0.0f;
    for (int j = 0; j < N; j += 8) {
        const float p0 = base[(size_t)(j + 0) * C];
        const float p1 = base[(size_t)(j + 1) * C];
        const float p2 = base[(size_t)(j + 2) * C];
        const float p3 = base[(size_t)(j + 3) * C];
        const float p4 = base[(size_t)(j + 4) * C];
        const float p5 = base[(size_t)(j + 5) * C];
        const float p6 = base[(size_t)(j + 6) * C];
        const float p7 = base[(size_t)(j + 7) * C];
        xacc += att_s[j+0]*p0 + att_s[j+1]*p1 + att_s[j+2]*p2 + att_s[j+3]*p3
              + att_s[j+4]*p4 + att_s[j+5]*p5 + att_s[j+6]*p6 + att_s[j+7]*p7;
    }

    const float x = xacc + n_g[i * C + t];
    float sq = x * x;
    #pragma unroll
    for (int off = 32; off > 0; off >>= 1)
        sq += __shfl_xor(sq, off, 64);
    if (lane == 0) part[wid] = sq;
    __syncthreads();
    const float nrm = sqrtf(part[0] + part[1] + part[2] + part[3]);
    out[i * C + t] = x / nrm;
}

// ---------------------------------------------------------------------------
// Fallback (small-ws) kernels: previous session's structure, original W layout.
// ---------------------------------------------------------------------------
__global__ __launch_bounds__(256) void k_scores_old(
    const float* __restrict__ n_g, const float* __restrict__ s_g,
    const float* __restrict__ v_g,
    const float* __restrict__ Wq, const float* __restrict__ bq,
    const float* __restrict__ Wk, const float* __restrict__ bk,
    float* __restrict__ scores)
{
    __shared__ float e_lds[TJ][C];
    __shared__ float part[4][TJ];
    const int i  = blockIdx.x;
    const int jb = blockIdx.y * TJ;
    const int t  = threadIdx.x;
    const int lane = t & 63, wid = t >> 6;

    const float ni = n_g[i * C + t];
    #pragma unroll
    for (int j = 0; j < TJ; ++j) {
        const int jj = jb + j;
        e_lds[j][t] = ni * n_g[jj * C + t] * s_g[((size_t)i * N + jj) * C + t];
    }
    __syncthreads();

    float accq[TJ], acck[TJ];
    const float bqd = bq[t], bkd = bk[t];
    #pragma unroll
    for (int j = 0; j < TJ; ++j) { accq[j] = bqd; acck[j] = bkd; }

    const float4* wq4 = (const float4*)(Wq + (size_t)t * C);
    const float4* wk4 = (const float4*)(Wk + (size_t)t * C);
    for (int c4 = 0; c4 < C / 4; ++c4) {
        const float4 wq = wq4[c4];
        const float4 wk = wk4[c4];
        #pragma unroll
        for (int j = 0; j < TJ; ++j) {
            const float4 ev = *(const float4*)&e_lds[j][c4 * 4];
            accq[j] += wq.x*ev.x + wq.y*ev.y + wq.z*ev.z + wq.w*ev.w;
            acck[j] += wk.x*ev.x + wk.y*ev.y + wk.z*ev.z + wk.w*ev.w;
        }
    }

    #pragma unroll
    for (int j = 0; j < TJ; ++j) {
        const int jj = jb + j;
        const float vv = v_g[((size_t)i * N + jj) * C + t];
        float r = accq[j] * acck[j] * vv * vv;
        #pragma unroll
        for (int off = 32; off > 0; off >>= 1)
            r += __shfl_down(r, off, 64);
        if (lane == 0) part[wid][j] = r;
    }
    __syncthreads();
    if (t < TJ) {
        const float ssum = part[0][t] + part[1][t] + part[2][t] + part[3][t];
        scores[(size_t)i * N + jb + t] = ssum * (1.0f / 16.0f);
    }
}

__global__ __launch_bounds__(256) void k_out(
    const float* __restrict__ n_g, const float* __restrict__ s_g,
    const float* __restrict__ v_g,
    const float* __restrict__ Wv, const float* __restrict__ bv,
    const float* __restrict__ attn, float* __restrict__ out)
{
    __shared__ float e_lds[TJ][C];
    __shared__ float part[4];
    const int i = blockIdx.x;
    const int t = threadIdx.x;
    const int lane = t & 63, wid = t >> 6;

    const float ni  = n_g[i * C + t];
    const float bvd = bv[t];
    const float4* wv4 = (const float4*)(Wv + (size_t)t * C);
    float xacc = 0.0f;

    for (int jt = 0; jt < N / TJ; ++jt) {
        const int jb = jt * TJ;
        __syncthreads();
        #pragma unroll
        for (int j = 0; j < TJ; ++j) {
            const int jj = jb + j;
            e_lds[j][t] = ni * n_g[jj * C + t] * s_g[((size_t)i * N + jj) * C + t];
        }
        __syncthreads();

        float accv[TJ];
        #pragma unroll
        for (int j = 0; j < TJ; ++j) accv[j] = bvd;

        float4 vn = wv4[0];
        for (int c4 = 0; c4 < C / 4; ++c4) {
            const float4 wv = vn;
            if (c4 + 1 < C / 4) vn = wv4[c4 + 1];
            #pragma unroll
            for (int j = 0; j < TJ; ++j) {
                const float4 ev = *(const float4*)&e_lds[j][c4 * 4];
                accv[j] += wv.x*ev.x + wv.y*ev.y + wv.z*ev.z + wv.w*ev.w;
            }
        }
        #pragma unroll
        for (int j = 0; j < TJ; ++j) {
            const int jj = jb + j;
            const float a  = attn[(size_t)i * N + jj];
            const float vd = v_g[((size_t)i * N + jj) * C + t];
            xacc += a * accv[j] * vd;
        }
    }

    const float x = xacc + ni;
    float sq = x * x;
    #pragma unroll
    for (int off = 32; off > 0; off >>= 1)
        sq += __shfl_xor(sq, off, 64);
    if (lane == 0) part[wid] = sq;
    __syncthreads();
    const float nrm = sqrtf(part[0] + part[1] + part[2] + part[3]);
    out[i * C + t] = x / nrm;
}

extern "C" void kernel_launch(void* const* d_in, const int* in_sizes, int n_in,
                              void* d_out, int out_size, void* d_ws, size_t ws_size,
                              hipStream_t stream)
{
    const float* n_g = (const float*)d_in[0];
    const float* s_g = (const float*)d_in[1];
    const float* v_g = (const float*)d_in[2];
    const float* Wq  = (const float*)d_in[3];
    const float* bq  = (const float*)d_in[4];
    const float* Wk  = (const float*)d_in[5];
    const float* bk  = (const float*)d_in[6];
    const float* Wv  = (const float*)d_in[7];
    const float* bv  = (const float*)d_in[8];
    float* out = (float*)d_out;

    const size_t score_bytes = (size_t)N * N * sizeof(float);            // 1 MB
    const size_t ve_bytes    = (size_t)N * N * C * sizeof(float);        // 268 MB
    const size_t wt_bytes    = (size_t)3 * C * C * sizeof(float);        // 768 KB

    float* scores = (float*)d_ws;

    if (ws_size >= score_bytes + ve_bytes + wt_bytes) {
        // Full path: transposed W + fused edge + veW + gather.
        float* veW = (float*)((char*)d_ws + score_bytes);
        float* wt  = (float*)((char*)d_ws + score_bytes + ve_bytes);
        float* wqt = wt;
        float* wkt = wt + (size_t)C * C;
        float* wvt = wt + (size_t)2 * C * C;

        k_transpose<<<dim3(C / 32, C / 32, 3), 256, 0, stream>>>(Wq, Wk, Wv, wt);
        k_edge<true><<<dim3(N, N / TJB), 256, 0, stream>>>(
            n_g, s_g, v_g, wqt, bq, wkt, bk, wvt, bv, scores, veW);
        k_softmax<<<N, 256, 0, stream>>>(scores);
        k_gather <<<N, 256, 0, stream>>>(n_g, veW, scores, out);
    } else if (ws_size >= score_bytes + wt_bytes) {
        // Medium path: new edge kernel (no veW) + recompute-style output.
        float* wt  = (float*)((char*)d_ws + score_bytes);
        float* wqt = wt;
        float* wkt = wt + (size_t)C * C;
        float* wvt = wt + (size_t)2 * C * C;

        k_transpose<<<dim3(C / 32, C / 32, 3), 256, 0, stream>>>(Wq, Wk, Wv, wt);
        k_edge<false><<<dim3(N, N / TJB), 256, 0, stream>>>(
            n_g, s_g, v_g, wqt, bq, wkt, bk, wvt, bv, scores, nullptr);
        k_softmax<<<N, 256, 0, stream>>>(scores);
        k_out    <<<N, 256, 0, stream>>>(n_g, s_g, v_g, Wv, bv, scores, out);
    } else {
        // Small-ws fallback: previous session's 3-kernel pipeline.
        k_scores_old<<<dim3(N, N / TJ), 256, 0, stream>>>(
            n_g, s_g, v_g, Wq, bq, Wk, bk, scores);
        k_softmax<<<N, 256, 0, stream>>>(scores);
        k_out    <<<N, 256, 0, stream>>>(n_g, s_g, v_g, Wv, bv, scores, out);
    }
}